// Round 1
// baseline (300.898 us; speedup 1.0000x reference)
//
#include <hip/hip_runtime.h>
#include <hip/hip_bf16.h>

typedef __attribute__((ext_vector_type(8))) short short8;
typedef __attribute__((ext_vector_type(4))) float f32x4;

constexpr int N = 1024, M = 1024, D = 64, BH = 128;
constexpr size_t ATTN_ELEMS = (size_t)BH * N * M;     // 134217728
constexpr size_t QKV_ELEMS  = (size_t)BH * N * D;     // 8388608

__device__ __forceinline__ short f2b(float x) {
    __hip_bfloat16 h = __float2bfloat16(x);
    return *reinterpret_cast<short*>(&h);
}

// scale = sum(w_pos) / sqrt(n_heads=16)
__global__ void scale_kernel(const float* __restrict__ w, float* __restrict__ out) {
    float v = w[threadIdx.x];            // 64 threads, one wave
#pragma unroll
    for (int o = 32; o > 0; o >>= 1) v += __shfl_down(v, o);
    if (threadIdx.x == 0) out[0] = v * 0.25f;
}

// pb[n*M+m] = dot(pos_enc[0,n,m,:], w) + b   (16 lanes per (n,m) pair, float4 each)
__global__ void posbias_kernel(const float* __restrict__ pos, const float* __restrict__ w,
                               const float* __restrict__ b, float* __restrict__ pb) {
    const int lane16 = threadIdx.x & 15;
    const f32x4 w4 = ((const f32x4*)w)[lane16];
    const float bias = b[0];
    const int gid = blockIdx.x * blockDim.x + threadIdx.x;
    const int group = gid >> 4;
    const int ngroups = (gridDim.x * blockDim.x) >> 4;
    for (int pair = group; pair < N * M; pair += ngroups) {
        f32x4 p = ((const f32x4*)pos)[(size_t)pair * 16 + lane16];
        float s = p[0]*w4[0] + p[1]*w4[1] + p[2]*w4[2] + p[3]*w4[3];
        s += __shfl_xor(s, 1);
        s += __shfl_xor(s, 2);
        s += __shfl_xor(s, 4);
        s += __shfl_xor(s, 8);
        if (lane16 == 0) pb[pair] = s + bias;
    }
}

// Per (b,h): attn = (K K^T) * scale + pb.  128x128 tile per block, K=64 in one shot.
// LDS rows are 128B; XOR-swizzle 16B slots with (row&7) to break bank conflicts.
__launch_bounds__(256)
__global__ void attn_kernel(const float* __restrict__ keys, const float* __restrict__ pb,
                            const float* __restrict__ scale_p, float* __restrict__ out) {
    __shared__ short lA[128 * 64];
    __shared__ short lB[128 * 64];
    const int batch = blockIdx.y;                 // 0..127
    const int tr = blockIdx.x >> 3, tc = blockIdx.x & 7;
    const float* __restrict__ Kb = keys + (size_t)batch * N * D;
    const int tid = threadIdx.x;

    // Stage A rows [tr*128,+128) and B rows [tc*128,+128), fp32 -> bf16.
#pragma unroll
    for (int i = 0; i < 4; i++) {
        const int slot = tid + i * 256;           // 0..1023
        const int row = slot >> 3, s16 = slot & 7;
        const f32x4* srcA = (const f32x4*)(Kb + (size_t)(tr * 128 + row) * D + s16 * 8);
        const f32x4* srcB = (const f32x4*)(Kb + (size_t)(tc * 128 + row) * D + s16 * 8);
        f32x4 a0 = srcA[0], a1 = srcA[1];
        f32x4 b0 = srcB[0], b1 = srcB[1];
        short8 pa, pq;
#pragma unroll
        for (int e = 0; e < 4; e++) { pa[e] = f2b(a0[e]); pa[4 + e] = f2b(a1[e]); }
#pragma unroll
        for (int e = 0; e < 4; e++) { pq[e] = f2b(b0[e]); pq[4 + e] = f2b(b1[e]); }
        const int sw = (s16 ^ (row & 7));
        *(short8*)&lA[row * 64 + sw * 8] = pa;
        *(short8*)&lB[row * 64 + sw * 8] = pq;
    }
    __syncthreads();

    const int lane = tid & 63, wv = tid >> 6;
    const int wr = wv >> 1, wc = wv & 1;          // 2x2 waves of 64x64
    const int frow = lane & 15;
    const int kslot = lane >> 4;                  // 16B slot within K

    short8 a0[4], a1[4], b0[4], b1[4];
#pragma unroll
    for (int i = 0; i < 4; i++) {
        const int row = wr * 64 + i * 16 + frow;
        a0[i] = *(const short8*)&lA[row * 64 + ((kslot)     ^ (row & 7)) * 8];
        a1[i] = *(const short8*)&lA[row * 64 + ((4 + kslot) ^ (row & 7)) * 8];
    }
#pragma unroll
    for (int j = 0; j < 4; j++) {
        const int row = wc * 64 + j * 16 + frow;
        b0[j] = *(const short8*)&lB[row * 64 + ((kslot)     ^ (row & 7)) * 8];
        b1[j] = *(const short8*)&lB[row * 64 + ((4 + kslot) ^ (row & 7)) * 8];
    }

    f32x4 acc[4][4] = {};
#pragma unroll
    for (int i = 0; i < 4; i++)
#pragma unroll
        for (int j = 0; j < 4; j++) {
            acc[i][j] = __builtin_amdgcn_mfma_f32_16x16x32_bf16(a0[i], b0[j], acc[i][j], 0, 0, 0);
            acc[i][j] = __builtin_amdgcn_mfma_f32_16x16x32_bf16(a1[i], b1[j], acc[i][j], 0, 0, 0);
        }

    const float scale = scale_p[0];
    const size_t obase = (size_t)batch * N * M;
    const int r0 = tr * 128 + wr * 64, c0 = tc * 128 + wc * 64;
#pragma unroll
    for (int i = 0; i < 4; i++)
#pragma unroll
        for (int j = 0; j < 4; j++) {
            const int col = c0 + j * 16 + (lane & 15);
            const int rbase = r0 + i * 16 + (lane >> 4) * 4;
#pragma unroll
            for (int r = 0; r < 4; r++) {
                const int row = rbase + r;
                out[obase + (size_t)row * M + col] = acc[i][j][r] * scale + pb[row * M + col];
            }
        }
}

extern "C" void kernel_launch(void* const* d_in, const int* in_sizes, int n_in,
                              void* d_out, int out_size, void* d_ws, size_t ws_size,
                              hipStream_t stream) {
    const float* queries = (const float*)d_in[0];
    const float* keys    = (const float*)d_in[1];
    const float* values  = (const float*)d_in[2];
    const float* pos_enc = (const float*)d_in[3];
    const float* w_pos   = (const float*)d_in[4];
    const float* b_pos   = (const float*)d_in[5];

    float* out  = (float*)d_out;
    // Stash pb (4MB) + scale in the q-region of d_out; the q memcpy overwrites
    // it afterwards (stream-serialized, deterministic).
    float* pb      = out + ATTN_ELEMS;
    float* scale_p = pb + (size_t)N * M;

    scale_kernel<<<dim3(1), dim3(64), 0, stream>>>(w_pos, scale_p);
    posbias_kernel<<<dim3(2048), dim3(256), 0, stream>>>(pos_enc, w_pos, b_pos, pb);
    attn_kernel<<<dim3(64, BH), dim3(256), 0, stream>>>(keys, pb, scale_p, out);

    // q, k, v are layout-identical reshapes: straight D2D copies.
    float* qout = out + ATTN_ELEMS;
    float* kout = qout + QKV_ELEMS;
    float* vout = kout + QKV_ELEMS;
    hipMemcpyAsync(qout, queries, QKV_ELEMS * sizeof(float), hipMemcpyDeviceToDevice, stream);
    hipMemcpyAsync(kout, keys,    QKV_ELEMS * sizeof(float), hipMemcpyDeviceToDevice, stream);
    hipMemcpyAsync(vout, values,  QKV_ELEMS * sizeof(float), hipMemcpyDeviceToDevice, stream);
}

// Round 2
// 278.372 us; speedup vs baseline: 1.0809x; 1.0809x over previous
//
#include <hip/hip_runtime.h>
#include <hip/hip_bf16.h>

typedef __attribute__((ext_vector_type(8))) short short8;
typedef __attribute__((ext_vector_type(4))) float f32x4;

constexpr int N = 1024, M = 1024, D = 64, BH = 128;
constexpr size_t ATTN_ELEMS = (size_t)BH * N * M;     // 134217728
constexpr size_t QKV_ELEMS  = (size_t)BH * N * D;     // 8388608
constexpr int PB_BLOCKS = 2048;                        // posbias blocks
constexpr int COPY_BLOCKS_PER = 256;                   // per q/k/v

__device__ __forceinline__ short f2b(float x) {
    __hip_bfloat16 h = __float2bfloat16(x);
    return *reinterpret_cast<short*>(&h);
}

// One fused prep kernel:
//   blocks [0, PB_BLOCKS)                     : pb[n,m] = pos_enc[n,m,:].w + b
//   blocks [PB_BLOCKS, PB_BLOCKS+ncopy)       : q/k/v pass-through copies
//   last block                                : scale = sum(w)/sqrt(16)
__global__ void prep_kernel(const float* __restrict__ q, const float* __restrict__ k,
                            const float* __restrict__ v, const float* __restrict__ pos,
                            const float* __restrict__ w, const float* __restrict__ b,
                            float* __restrict__ pb, float* __restrict__ scale_p,
                            float* __restrict__ qout, float* __restrict__ kout,
                            float* __restrict__ vout, int ncopy) {
    const int bid = blockIdx.x, tid = threadIdx.x;
    if (bid < PB_BLOCKS) {
        const int lane16 = tid & 15;
        const f32x4 w4 = ((const f32x4*)w)[lane16];
        const float bias = b[0];
        const int group = (bid * 256 + tid) >> 4;
        const int ngroups = (PB_BLOCKS * 256) >> 4;
        for (int pair = group; pair < N * M; pair += ngroups) {
            f32x4 p = __builtin_nontemporal_load((const f32x4*)pos + (size_t)pair * 16 + lane16);
            float s = p[0]*w4[0] + p[1]*w4[1] + p[2]*w4[2] + p[3]*w4[3];
            s += __shfl_xor(s, 1);
            s += __shfl_xor(s, 2);
            s += __shfl_xor(s, 4);
            s += __shfl_xor(s, 8);
            if (lane16 == 0) pb[pair] = s + bias;
        }
    } else if (bid < PB_BLOCKS + ncopy) {
        const int cid = bid - PB_BLOCKS;
        const int which = cid >> 8, lid = cid & 255;
        const f32x4* __restrict__ src = (which == 0) ? (const f32x4*)q
                                      : (which == 1) ? (const f32x4*)k : (const f32x4*)v;
        f32x4* __restrict__ dst = (which == 0) ? (f32x4*)qout
                                : (which == 1) ? (f32x4*)kout : (f32x4*)vout;
        const int nel4 = (int)(QKV_ELEMS / 4);
        for (int i = lid * 256 + tid; i < nel4; i += COPY_BLOCKS_PER * 256) {
            f32x4 x = __builtin_nontemporal_load(src + i);
            __builtin_nontemporal_store(x, dst + i);
        }
    } else {
        if (tid < 64) {
            float val = w[tid];
#pragma unroll
            for (int o = 32; o > 0; o >>= 1) val += __shfl_down(val, o);
            if (tid == 0) scale_p[0] = val * 0.25f;
        }
    }
}

// Per (b,h): attn = (K K^T) * scale + pb.  128x128 tile per block, 8 waves,
// each wave owns a 64x32 sub-tile (low VGPR -> high occupancy for write drain).
__launch_bounds__(512)
__global__ void attn_kernel(const float* __restrict__ keys, const float* __restrict__ pb,
                            const float* __restrict__ scale_p, float* __restrict__ out) {
    __shared__ short lA[128 * 64];
    __shared__ short lB[128 * 64];
    const int batch = blockIdx.y;
    const int tr = blockIdx.x >> 3, tc = blockIdx.x & 7;
    const float* __restrict__ Kb = keys + (size_t)batch * N * D;
    const int tid = threadIdx.x;
    const float scale = scale_p[0];

    // Stage A rows [tr*128,+128) and B rows [tc*128,+128), fp32 -> bf16,
    // 16B slots XOR-swizzled by (row&7) to break the 128B-row bank conflict.
#pragma unroll
    for (int i = 0; i < 2; i++) {
        const int slot = tid + i * 512;           // 0..1023
        const int row = slot >> 3, s16 = slot & 7;
        const f32x4* srcA = (const f32x4*)(Kb + (size_t)(tr * 128 + row) * D + s16 * 8);
        const f32x4* srcB = (const f32x4*)(Kb + (size_t)(tc * 128 + row) * D + s16 * 8);
        f32x4 a0 = srcA[0], a1 = srcA[1];
        f32x4 b0 = srcB[0], b1 = srcB[1];
        short8 pa, pq;
#pragma unroll
        for (int e = 0; e < 4; e++) { pa[e] = f2b(a0[e]); pa[4 + e] = f2b(a1[e]); }
#pragma unroll
        for (int e = 0; e < 4; e++) { pq[e] = f2b(b0[e]); pq[4 + e] = f2b(b1[e]); }
        const int sw = (s16 ^ (row & 7));
        *(short8*)&lA[row * 64 + sw * 8] = pa;
        *(short8*)&lB[row * 64 + sw * 8] = pq;
    }
    __syncthreads();

    const int lane = tid & 63, wv = tid >> 6;     // 8 waves
    const int wr = wv >> 2, wc = wv & 3;          // 2x4 waves of 64x32
    const int frow = lane & 15;
    const int kslot = lane >> 4;                  // 16B slot within K

    short8 a0[4], a1[4], b0[2], b1[2];
#pragma unroll
    for (int i = 0; i < 4; i++) {
        const int row = wr * 64 + i * 16 + frow;
        a0[i] = *(const short8*)&lA[row * 64 + ((kslot)     ^ (row & 7)) * 8];
        a1[i] = *(const short8*)&lA[row * 64 + ((4 + kslot) ^ (row & 7)) * 8];
    }
#pragma unroll
    for (int j = 0; j < 2; j++) {
        const int row = wc * 32 + j * 16 + frow;
        b0[j] = *(const short8*)&lB[row * 64 + ((kslot)     ^ (row & 7)) * 8];
        b1[j] = *(const short8*)&lB[row * 64 + ((4 + kslot) ^ (row & 7)) * 8];
    }

    f32x4 acc[4][2] = {};
#pragma unroll
    for (int i = 0; i < 4; i++)
#pragma unroll
        for (int j = 0; j < 2; j++) {
            acc[i][j] = __builtin_amdgcn_mfma_f32_16x16x32_bf16(a0[i], b0[j], acc[i][j], 0, 0, 0);
            acc[i][j] = __builtin_amdgcn_mfma_f32_16x16x32_bf16(a1[i], b1[j], acc[i][j], 0, 0, 0);
        }

    const size_t obase = (size_t)batch * N * M;
    const int r0 = tr * 128 + wr * 64, c0 = tc * 128 + wc * 32;
#pragma unroll
    for (int i = 0; i < 4; i++)
#pragma unroll
        for (int j = 0; j < 2; j++) {
            const int col = c0 + j * 16 + (lane & 15);
            const int rbase = r0 + i * 16 + (lane >> 4) * 4;
#pragma unroll
            for (int r = 0; r < 4; r++) {
                const int row = rbase + r;
                float val = acc[i][j][r] * scale + pb[row * M + col];
                __builtin_nontemporal_store(val, &out[obase + (size_t)row * M + col]);
            }
        }
}

extern "C" void kernel_launch(void* const* d_in, const int* in_sizes, int n_in,
                              void* d_out, int out_size, void* d_ws, size_t ws_size,
                              hipStream_t stream) {
    const float* queries = (const float*)d_in[0];
    const float* keys    = (const float*)d_in[1];
    const float* values  = (const float*)d_in[2];
    const float* pos_enc = (const float*)d_in[3];
    const float* w_pos   = (const float*)d_in[4];
    const float* b_pos   = (const float*)d_in[5];

    float* out  = (float*)d_out;
    float* qout = out + ATTN_ELEMS;
    float* kout = qout + QKV_ELEMS;
    float* vout = kout + QKV_ELEMS;

    const bool use_ws = ws_size >= ((size_t)N * M + 16) * sizeof(float);

    if (use_ws) {
        float* pb      = (float*)d_ws;
        float* scale_p = pb + (size_t)N * M;
        const int ncopy = 3 * COPY_BLOCKS_PER;
        prep_kernel<<<dim3(PB_BLOCKS + ncopy + 1), dim3(256), 0, stream>>>(
            queries, keys, values, pos_enc, w_pos, b_pos, pb, scale_p,
            qout, kout, vout, ncopy);
        attn_kernel<<<dim3(64, BH), dim3(512), 0, stream>>>(keys, pb, scale_p, out);
    } else {
        // Fallback: stash pb+scale in the q-region of d_out, copy q/k/v after.
        float* pb      = qout;
        float* scale_p = pb + (size_t)N * M;
        prep_kernel<<<dim3(PB_BLOCKS + 1), dim3(256), 0, stream>>>(
            queries, keys, values, pos_enc, w_pos, b_pos, pb, scale_p,
            qout, kout, vout, /*ncopy=*/0);
        attn_kernel<<<dim3(64, BH), dim3(512), 0, stream>>>(keys, pb, scale_p, out);
        hipMemcpyAsync(qout, queries, QKV_ELEMS * sizeof(float), hipMemcpyDeviceToDevice, stream);
        hipMemcpyAsync(kout, keys,    QKV_ELEMS * sizeof(float), hipMemcpyDeviceToDevice, stream);
        hipMemcpyAsync(vout, values,  QKV_ELEMS * sizeof(float), hipMemcpyDeviceToDevice, stream);
    }
}

// Round 3
// 271.699 us; speedup vs baseline: 1.1075x; 1.0246x over previous
//
#include <hip/hip_runtime.h>
#include <hip/hip_bf16.h>

typedef __attribute__((ext_vector_type(8))) short short8;
typedef __attribute__((ext_vector_type(4))) float f32x4;

constexpr int N = 1024, M = 1024, D = 64, BH = 128;
constexpr size_t ATTN_ELEMS = (size_t)BH * N * M;     // 134217728
constexpr size_t QKV_ELEMS  = (size_t)BH * N * D;     // 8388608
constexpr int PB_BLOCKS = 2048;                        // posbias blocks
constexpr int COPY_BLOCKS_PER = 256;                   // per q/k/v
constexpr int BGROUP = 8;                              // batches per attn block

__device__ __forceinline__ short f2b(float x) {
    __hip_bfloat16 h = __float2bfloat16(x);
    return *reinterpret_cast<short*>(&h);
}

// One fused prep kernel:
//   blocks [0, PB_BLOCKS)                     : pb[n,m] = pos_enc[n,m,:].w + b
//   blocks [PB_BLOCKS, PB_BLOCKS+ncopy)       : q/k/v pass-through copies
//   last block                                : scale = sum(w)/sqrt(16)
__global__ void prep_kernel(const float* __restrict__ q, const float* __restrict__ k,
                            const float* __restrict__ v, const float* __restrict__ pos,
                            const float* __restrict__ w, const float* __restrict__ b,
                            float* __restrict__ pb, float* __restrict__ scale_p,
                            float* __restrict__ qout, float* __restrict__ kout,
                            float* __restrict__ vout, int ncopy) {
    const int bid = blockIdx.x, tid = threadIdx.x;
    if (bid < PB_BLOCKS) {
        const int lane16 = tid & 15;
        const f32x4 w4 = ((const f32x4*)w)[lane16];
        const float bias = b[0];
        const int group = (bid * 256 + tid) >> 4;
        const int ngroups = (PB_BLOCKS * 256) >> 4;
        for (int pair = group; pair < N * M; pair += ngroups) {
            f32x4 p = __builtin_nontemporal_load((const f32x4*)pos + (size_t)pair * 16 + lane16);
            float s = p[0]*w4[0] + p[1]*w4[1] + p[2]*w4[2] + p[3]*w4[3];
            s += __shfl_xor(s, 1);
            s += __shfl_xor(s, 2);
            s += __shfl_xor(s, 4);
            s += __shfl_xor(s, 8);
            if (lane16 == 0) pb[pair] = s + bias;
        }
    } else if (bid < PB_BLOCKS + ncopy) {
        const int cid = bid - PB_BLOCKS;
        const int which = cid >> 8, lid = cid & 255;
        const f32x4* __restrict__ src = (which == 0) ? (const f32x4*)q
                                      : (which == 1) ? (const f32x4*)k : (const f32x4*)v;
        f32x4* __restrict__ dst = (which == 0) ? (f32x4*)qout
                                : (which == 1) ? (f32x4*)kout : (f32x4*)vout;
        const int nel4 = (int)(QKV_ELEMS / 4);
        for (int i = lid * 256 + tid; i < nel4; i += COPY_BLOCKS_PER * 256) {
            f32x4 x = __builtin_nontemporal_load(src + i);
            __builtin_nontemporal_store(x, dst + i);
        }
    } else {
        if (tid < 64) {
            float val = w[tid];
#pragma unroll
            for (int o = 32; o > 0; o >>= 1) val += __shfl_down(val, o);
            if (tid == 0) scale_p[0] = val * 0.25f;
        }
    }
}

// attn = (K K^T) * scale + pb, per (b,h). Each block owns one 128x64 output
// tile position for BGROUP consecutive batches; pb fragments are loaded ONCE
// into registers (32 VGPR) and reused, cutting pb HBM traffic 8x.
// 4 waves (2x2) of 64x32 sub-tiles; K strips staged fp32->bf16 into LDS with
// (row&7) XOR-swizzle on 16B slots.
__launch_bounds__(256)
__global__ void attn_kernel(const float* __restrict__ keys, const float* __restrict__ pb,
                            const float* __restrict__ scale_p, float* __restrict__ out) {
    __shared__ short lK[192 * 64];                // A: rows 0..127, B: rows 128..191
    const int tr = blockIdx.x >> 4, tc = blockIdx.x & 15;
    const int batch0 = blockIdx.y * BGROUP;
    const int tid = threadIdx.x;
    const float scale = scale_p[0];

    const int lane = tid & 63, wv = tid >> 6;     // 4 waves
    const int wr = wv >> 1, wc = wv & 1;          // 2x2 waves of 64x32
    const int frow = lane & 15;
    const int kslot = lane >> 4;

    const int r0 = tr * 128 + wr * 64;            // output row base (this wave)
    const int c0 = tc * 64 + wc * 32;             // output col base (this wave)
    const int ocol = c0 + (lane & 15);            // col offset w/o j
    const int orow = r0 + (lane >> 4) * 4;        // row offset w/o i,r

    // Preload pb fragments in accumulator layout — reused for all BGROUP batches.
    f32x4 pf[4][2];
#pragma unroll
    for (int i = 0; i < 4; i++)
#pragma unroll
        for (int j = 0; j < 2; j++)
#pragma unroll
            for (int r = 0; r < 4; r++)
                pf[i][j][r] = pb[(size_t)(orow + i * 16 + r) * M + (ocol + j * 16)];

    for (int t = 0; t < BGROUP; ++t) {
        const float* __restrict__ Kb = keys + (size_t)(batch0 + t) * N * D;

        // Stage A rows [tr*128,+128) and B rows [tc*64,+64), fp32 -> bf16.
#pragma unroll
        for (int it = 0; it < 6; ++it) {
            const int slot = it * 256 + tid;      // 0..1535
            const int row = slot >> 3, s16 = slot & 7;
            const int gr = (row < 128) ? (tr * 128 + row) : (tc * 64 + (row - 128));
            const f32x4* src = (const f32x4*)(Kb + (size_t)gr * D + s16 * 8);
            f32x4 x0 = src[0], x1 = src[1];
            short8 pk;
#pragma unroll
            for (int e = 0; e < 4; e++) { pk[e] = f2b(x0[e]); pk[4 + e] = f2b(x1[e]); }
            *(short8*)&lK[row * 64 + (s16 ^ (row & 7)) * 8] = pk;
        }
        __syncthreads();

        f32x4 acc[4][2] = {};
#pragma unroll
        for (int h = 0; h < 2; ++h) {             // k-split halves (k=0..31, 32..63)
            short8 a[4], bf[2];
#pragma unroll
            for (int i = 0; i < 4; i++) {
                const int ra = wr * 64 + i * 16 + frow;
                a[i] = *(const short8*)&lK[ra * 64 + ((h * 4 + kslot) ^ (ra & 7)) * 8];
            }
#pragma unroll
            for (int j = 0; j < 2; j++) {
                const int rb = 128 + wc * 32 + j * 16 + frow;
                bf[j] = *(const short8*)&lK[rb * 64 + ((h * 4 + kslot) ^ (rb & 7)) * 8];
            }
#pragma unroll
            for (int i = 0; i < 4; i++)
#pragma unroll
                for (int j = 0; j < 2; j++)
                    acc[i][j] = __builtin_amdgcn_mfma_f32_16x16x32_bf16(a[i], bf[j], acc[i][j], 0, 0, 0);
        }

        const size_t obase = (size_t)(batch0 + t) * N * M;
#pragma unroll
        for (int i = 0; i < 4; i++)
#pragma unroll
            for (int j = 0; j < 2; j++)
#pragma unroll
                for (int r = 0; r < 4; r++) {
                    float val = acc[i][j][r] * scale + pf[i][j][r];
                    __builtin_nontemporal_store(val,
                        &out[obase + (size_t)(orow + i * 16 + r) * M + (ocol + j * 16)]);
                }
        __syncthreads();                          // LDS safe to overwrite next t
    }
}

extern "C" void kernel_launch(void* const* d_in, const int* in_sizes, int n_in,
                              void* d_out, int out_size, void* d_ws, size_t ws_size,
                              hipStream_t stream) {
    const float* queries = (const float*)d_in[0];
    const float* keys    = (const float*)d_in[1];
    const float* values  = (const float*)d_in[2];
    const float* pos_enc = (const float*)d_in[3];
    const float* w_pos   = (const float*)d_in[4];
    const float* b_pos   = (const float*)d_in[5];

    float* out  = (float*)d_out;
    float* qout = out + ATTN_ELEMS;
    float* kout = qout + QKV_ELEMS;
    float* vout = kout + QKV_ELEMS;

    const bool use_ws = ws_size >= ((size_t)N * M + 16) * sizeof(float);

    if (use_ws) {
        float* pb      = (float*)d_ws;
        float* scale_p = pb + (size_t)N * M;
        const int ncopy = 3 * COPY_BLOCKS_PER;
        prep_kernel<<<dim3(PB_BLOCKS + ncopy + 1), dim3(256), 0, stream>>>(
            queries, keys, values, pos_enc, w_pos, b_pos, pb, scale_p,
            qout, kout, vout, ncopy);
        attn_kernel<<<dim3(128, BH / BGROUP), dim3(256), 0, stream>>>(keys, pb, scale_p, out);
    } else {
        // Fallback: stash pb+scale in the q-region of d_out, copy q/k/v after.
        float* pb      = qout;
        float* scale_p = pb + (size_t)N * M;
        prep_kernel<<<dim3(PB_BLOCKS + 1), dim3(256), 0, stream>>>(
            queries, keys, values, pos_enc, w_pos, b_pos, pb, scale_p,
            qout, kout, vout, /*ncopy=*/0);
        attn_kernel<<<dim3(128, BH / BGROUP), dim3(256), 0, stream>>>(keys, pb, scale_p, out);
        hipMemcpyAsync(qout, queries, QKV_ELEMS * sizeof(float), hipMemcpyDeviceToDevice, stream);
        hipMemcpyAsync(kout, keys,    QKV_ELEMS * sizeof(float), hipMemcpyDeviceToDevice, stream);
        hipMemcpyAsync(vout, values,  QKV_ELEMS * sizeof(float), hipMemcpyDeviceToDevice, stream);
    }
}